// Round 10
// baseline (320.079 us; speedup 1.0000x reference)
//
#include <hip/hip_runtime.h>

// B=64, IN=1024, OUT=1024, T=256
// syn[b,o,t] = sum_i W[o,i]*x[b,i,t]; spikes via f64 LIF scan.
//
// R20: (a) fused GEMM goes 4-wave / 1-wave-per-SIMD (512-VGPR budget):
// wave tile 64(o)x64(t), acc = 16 v16i (256 AGPR), 16KB LDS reads per 40
// MFMAs (0.4 KB/MFMA vs 0.6) -> block reads 96->64KB/step. Step model
// (R11-R19, <8% err): 1464 MFMA + 753 LDS + 470 DMA + ~300 scan/misc ->
// ~159us. Staging: 10 gload_lds16/thread/step, segment s=4j+wave, vmcnt(10).
// (b) k_beta deleted: slice_x computes beta inline from part (4KB/block)
// and ib==0 blocks write beta_e for the fused kernel. 3 launches total.
// Unchanged: 4-digit Ozaki p+q<=3, triple buffer 3x40KB, counted vmcnt,
// setprio, XCD b-swizzle, de-aliased select-form reg scan.
// Fallback: R6 f64-MFMA + standalone scan.

#define B_DIM 64
#define IN_DIM 1024
#define OUT_DIM 1024
#define T_DIM 256

typedef int v4i __attribute__((ext_vector_type(4)));
typedef int v16i __attribute__((ext_vector_type(16)));
typedef double v4d __attribute__((ext_vector_type(4)));

// ---------------- workspace layout (bytes) ----------------
#define LO_OFF   0ull                    // 67108864  f32 syn_lo (fallback only)
#define WSL_OFF  67108864ull             // i8 W frags [p:4][o32:32][ks:32][lane:64][16] = 4MB
#define XSL_OFF  73400320ull             // i8 x frags [q:4][b:64][t32:8][ks:32][lane:64][16] = 67MB
#define AL_OFF   174063616ull            // 4096      i32 alpha_e[1024]
#define BE_OFF   174067712ull            // 65536     i32 beta_e[64][256]
#define PART_OFF 174133248ull            // 1048576   f32 partial maxes [64][16][256]
#define WS_NEED  175181824ull

__device__ __forceinline__ void gload_lds16(const void* g, void* l)
{
    __builtin_amdgcn_global_load_lds(
        (const __attribute__((address_space(1))) void*)g,
        (__attribute__((address_space(3))) void*)l, 16, 0, 0);
}

// Integer digit extraction: fix28 = |x|/2^e_col * 2^28 (truncated), digits =
// 7-bit slices, negated if x<0. Bit-identical to the proven f64 trunc loop.
__device__ __forceinline__ void dig4_extract(unsigned bits, int bem,
                                             signed char* d /*4*/)
{
    const int be = (bits >> 23) & 255;
    unsigned M = (bits & 0x7fffffu) | (be ? 0x800000u : 0u);
    const int sh = be - bem + 4;
    unsigned fix = 0;
    if (sh >= 0) fix = M << sh;
    else if (sh > -32) fix = M >> (-sh);
    int d0 = (fix >> 21) & 127, d1 = (fix >> 14) & 127,
        d2 = (fix >> 7) & 127,  d3 = fix & 127;
    if (bits & 0x80000000u) { d0 = -d0; d1 = -d1; d2 = -d2; d3 = -d3; }
    d[0] = (signed char)d0; d[1] = (signed char)d1;
    d[2] = (signed char)d2; d[3] = (signed char)d3;
}

// ---------------- K1: dual-role aux (slice_w | beta_part) ----------------
__global__ __launch_bounds__(256) void k_aux_wx(
    const float* __restrict__ W, signed char* __restrict__ wsl,
    int* __restrict__ alpha_e,
    const float* __restrict__ x, float* __restrict__ part)
{
    __shared__ float red[256];
    __shared__ float wrow[1024];
    __shared__ int se;
    __shared__ float4 bp[4][64];
    const int tid = threadIdx.x;

    if (blockIdx.x < 1024) {
        // ---- slice_w (proven R15) ----
        const int o = blockIdx.x;
        float4 v = *(const float4*)&W[(size_t)o * IN_DIM + tid * 4];
        *(float4*)&wrow[tid * 4] = v;
        float m = fmaxf(fmaxf(fabsf(v.x), fabsf(v.y)), fmaxf(fabsf(v.z), fabsf(v.w)));
        red[tid] = m; __syncthreads();
        for (int s = 128; s > 0; s >>= 1) {
            if (tid < s) red[tid] = fmaxf(red[tid], red[tid + s]);
            __syncthreads();
        }
        if (tid == 0) { int e = 0; if (red[0] > 0.f) frexpf(red[0], &e); se = e; alpha_e[o] = e; }
        __syncthreads();
        if (tid >= 64) return;
        const int bem = se + 126;
        const int ks = tid >> 1, khalf = tid & 1;
        const int k0 = tid * 16;
        const int lane = (o & 31) + 32 * khalf;

        signed char dig[16][4];
        #pragma unroll
        for (int j = 0; j < 16; ++j)
            dig4_extract(__float_as_uint(wrow[k0 + j]), bem, dig[j]);

        #pragma unroll
        for (int p = 0; p < 4; ++p) {
            int w[4];
            #pragma unroll
            for (int g = 0; g < 4; ++g)
                w[g] = (dig[4*g][p] & 0xff) | ((dig[4*g+1][p] & 0xff) << 8) |
                       ((dig[4*g+2][p] & 0xff) << 16) | ((dig[4*g+3][p] & 0xff) << 24);
            const size_t base =
                (((size_t)p * 32 + (o >> 5)) * 32 + ks) * 1024 + lane * 16;
            *(v4i*)&wsl[base] = (v4i){w[0], w[1], w[2], w[3]};
        }
    } else {
        // ---- beta_part, float4 ----
        const int idx = blockIdx.x - 1024;
        const int ic = idx & 15, b = idx >> 4;
        const int quarter = tid >> 6, t4 = (tid & 63) * 4;
        const float* p = x + ((size_t)b * IN_DIM + ic * 64 + quarter * 16) * T_DIM + t4;
        float4 m4 = make_float4(0.f, 0.f, 0.f, 0.f);
        #pragma unroll
        for (int r = 0; r < 16; ++r) {
            float4 v = *(const float4*)&p[(size_t)r * T_DIM];
            m4.x = fmaxf(m4.x, fabsf(v.x)); m4.y = fmaxf(m4.y, fabsf(v.y));
            m4.z = fmaxf(m4.z, fabsf(v.z)); m4.w = fmaxf(m4.w, fabsf(v.w));
        }
        bp[quarter][tid & 63] = m4;
        __syncthreads();
        if (tid < 64) {
            float4 a = bp[0][tid], b4 = bp[1][tid], c = bp[2][tid], d = bp[3][tid];
            float4 r;
            r.x = fmaxf(fmaxf(a.x, b4.x), fmaxf(c.x, d.x));
            r.y = fmaxf(fmaxf(a.y, b4.y), fmaxf(c.y, d.y));
            r.z = fmaxf(fmaxf(a.z, b4.z), fmaxf(c.z, d.z));
            r.w = fmaxf(fmaxf(a.w, b4.w), fmaxf(c.w, d.w));
            *(float4*)&part[((size_t)b * 16 + ic) * T_DIM + tid * 4] = r;
        }
    }
}

// ---------------- K2: slice x (4 digits) + inline beta from part -----------
// Deletes the k_beta kernel: threads<64 reduce part[b][0..16][t] -> e; ib==0
// blocks also publish beta_e[b][t] for the fused kernel (disjoint writes).
__global__ __launch_bounds__(256) void k_slice_x(const float* __restrict__ x,
    const float* __restrict__ part, int* __restrict__ beta_e,
    signed char* __restrict__ xsl)
{
    __shared__ float ft[64][68];   // float4-aligned rows, read 2-way free
    __shared__ int se_arr[64];
    const int tb = blockIdx.x;    // 0..3
    const int ib = blockIdx.y;    // 0..15
    const int b  = blockIdx.z;
    const int tid = threadIdx.x;
    const int t0 = tb * 64, i0 = ib * 64;
    #pragma unroll
    for (int p = 0; p < 4; ++p) {
        int id4 = tid + p * 256;           // 0..1023 float4 slots
        int il = id4 >> 4, c4 = (id4 & 15) * 4;
        float4 v = *(const float4*)&x[((size_t)b * IN_DIM + i0 + il) * T_DIM + t0 + c4];
        *(float4*)&ft[il][c4] = v;
    }
    if (tid < 64) {
        const int t = t0 + tid;
        float m = 0.f;
        #pragma unroll
        for (int ic = 0; ic < 16; ++ic)
            m = fmaxf(m, part[((size_t)b * 16 + ic) * T_DIM + t]);
        int e = 0;
        if (m > 0.f) frexpf(m, &e);
        se_arr[tid] = e;
        if (ib == 0) beta_e[b * T_DIM + t] = e;
    }
    __syncthreads();

    const int t32l = tid >> 7;
    const int ksl  = (tid >> 6) & 1;
    const int lane = tid & 63;
    const int t_local = t32l * 32 + (lane & 31);
    const int k_local = ksl * 32 + (lane >> 5) * 16;
    const int bem = se_arr[t_local] + 126;

    signed char dig[16][4];
    #pragma unroll
    for (int j = 0; j < 16; ++j)
        dig4_extract(__float_as_uint(ft[k_local + j][t_local]), bem, dig[j]);

    #pragma unroll
    for (int p = 0; p < 4; ++p) {
        int w[4];
        #pragma unroll
        for (int g = 0; g < 4; ++g)
            w[g] = (dig[4*g][p] & 0xff) | ((dig[4*g+1][p] & 0xff) << 8) |
                   ((dig[4*g+2][p] & 0xff) << 16) | ((dig[4*g+3][p] & 0xff) << 24);
        const size_t base =
            ((((size_t)p * B_DIM + b) * 8 + (tb * 2 + t32l)) * 32 + (ib * 2 + ksl)) * 1024
            + lane * 16;
        *(v4i*)&xsl[base] = (v4i){w[0], w[1], w[2], w[3]};
    }
}

// ---------------- K4: fused Ozaki i8 GEMM + LIF scan (4-wave) --------------
// Block 64(o)x256(t), 1D grid 1024, XCD swizzle b=(r&7)*8+(r>>3), ob=bid>>6.
// 4 waves, 1/SIMD (512-VGPR budget): wave w owns o 0..63 x t [64w,64w+64)
// (t32 pair 2w, 2w+1). Per wave/step: 8 af + 8 bf reads (16KB), 40 MFMAs,
// acc[osub:2][tsub:2][s:4] = 16 v16i. Staging: 10 loads/thread/step,
// segment s = 4j + wave at LDS off s*1024 = wave*1024 + j*4096; s<8 -> A
// [p=s>>1][osub=s&1], s>=8 -> u=s-8, B [q=u>>3][t32=u&7]. vmcnt(10) steady,
// drain once at kt=30 (R11-R19 ledger shape).
#define OZ_LOADS(PF)                                                        \
    {                                                                       \
        _Pragma("unroll")                                                   \
        for (int j = 0; j < 10; ++j) {                                      \
            gload_lds16(gp[j], &LB[PF][lbase + j * 4096]);                  \
            gp[j] += 1024;                                                  \
        }                                                                   \
    }

#define OZ_MATH(CUR)                                                        \
    {                                                                       \
        const signed char* base_ = LB[CUR];                                 \
        v4i af[4][2];                                                       \
        _Pragma("unroll")                                                   \
        for (int p = 0; p < 4; ++p)                                         \
            _Pragma("unroll")                                               \
            for (int os = 0; os < 2; ++os)                                  \
                af[p][os] = *(const v4i*)(base_ + p * 2048 + os * 1024 + l16); \
        __builtin_amdgcn_s_setprio(1);                                      \
        _Pragma("unroll")                                                   \
        for (int q = 0; q < 4; ++q) {                                       \
            v4i b0 = *(const v4i*)(base_ + 8192 + q * 8192 + t32a * 1024 + l16); \
            v4i b1 = *(const v4i*)(base_ + 8192 + q * 8192 + t32a * 1024 + 1024 + l16); \
            _Pragma("unroll")                                               \
            for (int p = 0; p + q < 4; ++p)                                 \
                _Pragma("unroll")                                           \
                for (int os = 0; os < 2; ++os) {                            \
                    accA[os][p + q] = __builtin_amdgcn_mfma_i32_32x32x32_i8( \
                        af[p][os], b0, accA[os][p + q], 0, 0, 0);           \
                    accB[os][p + q] = __builtin_amdgcn_mfma_i32_32x32x32_i8( \
                        af[p][os], b1, accB[os][p + q], 0, 0, 0);           \
                }                                                           \
        }                                                                   \
        __builtin_amdgcn_s_setprio(0);                                      \
    }

#define VMBAR(N)                                                            \
    do {                                                                    \
        asm volatile("s_waitcnt vmcnt(" #N ")" ::: "memory");               \
        __builtin_amdgcn_s_barrier();                                       \
    } while (0)

__global__ __launch_bounds__(256, 1) void k_oz_gemm_fused(
    const signed char* __restrict__ wsl, const signed char* __restrict__ xsl,
    const int* __restrict__ alpha_e, const int* __restrict__ beta_e,
    float* __restrict__ out)
{
    __shared__ __align__(16) signed char LB[3][40960];

    const int tid = threadIdx.x;
    const int lane = tid & 63, wave = tid >> 6;    // wave 0..3
    const int bid = blockIdx.x;
    const int ob = bid >> 6;                       // 0..15 (o block of 64)
    const int rr = bid & 63;
    const int b  = ((rr & 7) << 3) + (rr >> 3);    // bijective XCD swizzle
    const int o0 = ob * 64;
    const int t32a = 2 * wave;                     // first t32 of this wave
    const int l16 = lane * 16;

    v16i accA[2][4], accB[2][4];   // [osub][s]; A = tsub0, B = tsub1
    #pragma unroll
    for (int os = 0; os < 2; ++os)
        #pragma unroll
        for (int s = 0; s < 4; ++s) {
            accA[os][s] = (v16i){0,0,0,0,0,0,0,0,0,0,0,0,0,0,0,0};
            accB[os][s] = (v16i){0,0,0,0,0,0,0,0,0,0,0,0,0,0,0,0};
        }

    // Staging pointers: segment s = 4j + wave (j=0..9).
    const signed char* gp[10];
    #pragma unroll
    for (int j = 0; j < 10; ++j) {
        const int s = 4 * j + wave;
        if (s < 8) {
            gp[j] = wsl + ((size_t)(s >> 1) << 20)
                        + ((size_t)(2 * ob + (s & 1)) << 15) + l16;
        } else {
            const int u = s - 8;
            gp[j] = xsl + ((size_t)(u >> 3) << 24) + ((size_t)b << 18)
                        + ((size_t)(u & 7) << 15) + l16;
        }
    }
    const int lbase = wave * 1024;   // segment s LDS offset = s*1024

    // prologue: kt=0 -> LB[0], kt=1 -> LB[1]; retire kt=0 (vmcnt 20->10).
    OZ_LOADS(0)
    OZ_LOADS(1)
    VMBAR(10);

    // steady state: kt = 0..29, buffers rotate (0,1,2). Never drain to 0.
    #pragma unroll 1
    for (int it = 0; it < 10; ++it) {
        OZ_LOADS(2) OZ_MATH(0) VMBAR(10);
        OZ_LOADS(0) OZ_MATH(1) VMBAR(10);
        OZ_LOADS(1) OZ_MATH(2) VMBAR(10);
    }
    // kt=30: drain kt=31's 10 loads, last barrier.
    OZ_MATH(0) VMBAR(0);
    // kt=31: registers only.
    OZ_MATH(1)

    // Runtime D-placement probes (R6/R7 technique).
    const int lr = lane & 31;
    const int rv = (lr + 1) * 0x01010101;
    const v4i pav  = {rv, rv, rv, rv};
    const v4i onev = {0x01010101, 0x01010101, 0x01010101, 0x01010101};
    const v16i z = (v16i){0,0,0,0,0,0,0,0,0,0,0,0,0,0,0,0};
    v16i d1 = __builtin_amdgcn_mfma_i32_32x32x32_i8(pav, onev, z, 0, 0, 0);
    v16i d2 = __builtin_amdgcn_mfma_i32_32x32x32_i8(onev, pav, z, 0, 0, 0);

    const int col = (d2[0] >> 5) - 1;            // 0..31 within tile
    const int gtA = wave * 64 + col;             // t of accA column (tsub0)
    const int gtB = gtA + 32;                    // accB column (tsub1)
    const int ebA = beta_e[b * T_DIM + gtA];
    const int ebB = beta_e[b * T_DIM + gtB];

    // Exact f64 syn; acc dies here.
    const double C0 = 0x1p-14, C1 = 0x1p-21, C2 = 0x1p-28, C3 = 0x1p-35;
    double synA_[2][16], synB_[2][16];
    int row_[16];
    #pragma unroll
    for (int r = 0; r < 16; ++r) {
        row_[r] = (d1[r] >> 5) - 1;              // 0..31 within tile
        #pragma unroll
        for (int os = 0; os < 2; ++os) {
            const int go = os * 32 + row_[r];
            const int ea = alpha_e[o0 + go];
            double vA = (double)accA[os][0][r] * C0 + (double)accA[os][1][r] * C1 +
                        (double)accA[os][2][r] * C2 + (double)accA[os][3][r] * C3;
            double vB = (double)accB[os][0][r] * C0 + (double)accB[os][1][r] * C1 +
                        (double)accB[os][2][r] * C2 + (double)accB[os][3][r] * C3;
            synA_[os][r] = ldexp(vA, ea + ebA);
            synB_[os][r] = ldexp(vB, ea + ebB);
        }
    }

    // ---- fused LIF scan over 4 t-chunks of 64 (chunk c = wave c's range) --
    double* synbuf = (double*)&LB[0][0];   // [t:64][o:65]
    float*  spkbuf = (float*)&LB[1][0];    // [o:64][68] (float4-aligned rows)
    float*  outp = out + ((size_t)b * OUT_DIM + o0) * T_DIM;
    double mem = 0.0;                      // valid in wave 0 lanes (o-rows)

    __syncthreads();
    #pragma unroll 1
    for (int c = 0; c < 4; ++c) {
        if (wave == c) {
            #pragma unroll
            for (int r = 0; r < 16; ++r)
                #pragma unroll
                for (int os = 0; os < 2; ++os) {
                    const int go = os * 32 + row_[r];
                    synbuf[(size_t)col * 65 + go]        = synA_[os][r];
                    synbuf[(size_t)(col + 32) * 65 + go] = synB_[os][r];
                }
        }
        __syncthreads();
        if (wave == 0) {
            // batch-16 reg reads -> short select-form chain -> packed writes.
            float sp[64];
            #pragma unroll
            for (int g = 0; g < 4; ++g) {
                double sv[16];
                #pragma unroll
                for (int k = 0; k < 16; ++k)
                    sv[k] = synbuf[(size_t)(g * 16 + k) * 65 + lane];
                #pragma unroll
                for (int k = 0; k < 16; ++k) {
                    double a = 0.9 * mem + sv[k];          // same eval order
                    mem = (mem > 1.0) ? (a - 1.0) : a;     // reset uses OLD mem
                    sp[g * 16 + k] = (mem > 1.0) ? 1.0f : 0.0f;
                }
            }
            #pragma unroll
            for (int k4 = 0; k4 < 16; ++k4)
                *(float4*)&spkbuf[lane * 68 + k4 * 4] = make_float4(
                    sp[k4 * 4], sp[k4 * 4 + 1], sp[k4 * 4 + 2], sp[k4 * 4 + 3]);
        }
        __syncthreads();
        {
            const int o = tid >> 2, tg = tid & 3;          // 4 float4 / thread
            float* dst = outp + (size_t)o * T_DIM + c * 64;
            #pragma unroll
            for (int k = 0; k < 4; ++k) {
                float4 v = *(float4*)&spkbuf[o * 68 + tg * 16 + k * 4];
                *(float4*)&dst[tg * 16 + k * 4] = v;
            }
        }
        __syncthreads();
    }
}

// ---------------- Fallback GEMM: R6 f64-MFMA with probes (proven) ----------
#define BM 128
#define BN 128
#define BK 16
#define LDA 130

__global__ __launch_bounds__(256, 2) void spk_gemm_mfma64p_kernel(
    const float* __restrict__ x, const float* __restrict__ W,
    float* __restrict__ syn_hi, float* __restrict__ syn_lo)
{
    const int tid  = threadIdx.x;
    const int lane = tid & 63;
    const int wave = tid >> 6;
    const int tb = blockIdx.x, ob = blockIdx.y, b = blockIdx.z;

    __shared__ __align__(16) double As[BK][LDA];
    __shared__ __align__(16) double Bs[BK][LDA];

    const v4d zz = {0.0, 0.0, 0.0, 0.0};
    v4d d1 = __builtin_amdgcn_mfma_f64_16x16x4f64((double)lane, 1.0, zz, 0, 0, 0);
    v4d d2 = __builtin_amdgcn_mfma_f64_16x16x4f64(1.0, (double)lane, zz, 0, 0, 0);
    const bool a_h1 = (((int)d1[0] & 3) == 0);
    const bool b_h1 = (((int)d2[0] & 3) == 0);
    int drow[4];
    #pragma unroll
    for (int r = 0; r < 4; ++r) {
        const int v = (int)d1[r];
        drow[r] = (a_h1 ? (v - 96) >> 2 : (v - 6) >> 4) & 15;
    }
    const int am = a_h1 ? (lane & 15) : (lane >> 2);
    const int ak = a_h1 ? (lane >> 4) : (lane & 3);
    const int bn = b_h1 ? (lane & 15) : (lane >> 2);
    const int bk = b_h1 ? (lane >> 4) : (lane & 3);
    const int dcol = lane & 15;

    const int o0 = ob * BM, t0 = tb * BN;
    const float* Wp = W + (size_t)o0 * IN_DIM;
    const float* xp = x + (size_t)b * IN_DIM * T_DIM + t0;
    const int wo = (wave >> 1) * 64, wt = (wave & 1) * 64;

    v4d acc[4][4];
    #pragma unroll
    for (int i = 0; i < 4; ++i)
        #pragma unroll
        for (int j = 0; j < 4; ++j) acc[i][j] = zz;

    const int ar0 = tid / 4, ac = (tid % 4) * 4;
    const int bkr0 = tid / 32, btc = (tid % 32) * 4;

    float4 pa[2], pb[2];
    #pragma unroll
    for (int p = 0; p < 2; ++p) {
        pa[p] = *(const float4*)&Wp[(size_t)(ar0 + p * 64) * IN_DIM + ac];
        pb[p] = *(const float4*)&xp[(size_t)(bkr0 + p * 8) * T_DIM + btc];
    }

    for (int k0 = 0; k0 < IN_DIM; k0 += BK) {
        #pragma unroll
        for (int p = 0; p < 2; ++p) {
            const int r = ar0 + p * 64;
            As[ac + 0][r] = (double)pa[p].x; As[ac + 1][r] = (double)pa[p].y;
            As[ac + 2][r] = (double)pa[p].z; As[ac + 3][r] = (double)pa[p].w;
            const int kr = bkr0 + p * 8;
            Bs[kr][btc + 0] = (double)pb[p].x; Bs[kr][btc + 1] = (double)pb[p].y;
            Bs[kr][btc + 2] = (double)pb[p].z; Bs[kr][btc + 3] = (double)pb[p].w;
        }
        if (k0 + BK < IN_DIM) {
            #pragma unroll
            for (int p = 0; p < 2; ++p) {
                pa[p] = *(const float4*)&Wp[(size_t)(ar0 + p * 64) * IN_DIM + k0 + BK + ac];
                pb[p] = *(const float4*)&xp[(size_t)(bkr0 + p * 8 + k0 + BK) * T_DIM + btc];
            }
        }
        __syncthreads();
        #pragma unroll
        for (int kk = 0; kk < 4; ++kk) {
            const int kra = kk * 4 + ak, krb = kk * 4 + bk;
            double a[4], bb[4];
            #pragma unroll
            for (int i = 0; i < 4; ++i) a[i] = As[kra][wo + i * 16 + am];
            #pragma unroll
            for (int j = 0; j < 4; ++j) bb[j] = Bs[krb][wt + j * 16 + bn];
            #pragma unroll
            for (int i = 0; i < 4; ++i)
                #pragma unroll
                for (int j = 0; j < 4; ++j)
                    acc[i][j] = __builtin_amdgcn_mfma_f64_16x16x4f64(a[i], bb[j], acc[i][j], 0, 0, 0);
        }
        __syncthreads();
    }

    float* ohi = syn_hi + ((size_t)b * OUT_DIM + o0) * T_DIM + t0;
    float* olo = syn_lo + ((size_t)b * OUT_DIM + o0) * T_DIM + t0;
    #pragma unroll
    for (int i = 0; i < 4; ++i)
        #pragma unroll
        for (int j = 0; j < 4; ++j) {
            const int col = wt + j * 16 + dcol;
            #pragma unroll
            for (int r = 0; r < 4; ++r) {
                double s = acc[i][j][r];
                float hi = (float)s;
                float lo = (float)(s - (double)hi);
                const size_t off = (size_t)(wo + i * 16 + drow[r]) * T_DIM + col;
                ohi[off] = hi; olo[off] = lo;
            }
        }
}

// ---------------- scan: f64 LIF, in place over hi (fallback only) ----------
__global__ __launch_bounds__(256) void spk_scan_f64_kernel(
    float* __restrict__ hi, const float* __restrict__ lo)
{
    const int TC = 16;
    __shared__ float thi[256][TC + 1];
    __shared__ float tlo[256][TC + 1];
    const int tid = threadIdx.x;
    const size_t row0 = (size_t)blockIdx.x * 256;

    double mem = 0.0;
    for (int t0 = 0; t0 < T_DIM; t0 += TC) {
        #pragma unroll
        for (int p = 0; p < 4; ++p) {
            int id = tid + p * 256;
            int r = id / 4, c = (id % 4) * 4;
            size_t g = (row0 + r) * T_DIM + t0 + c;
            float4 vh = *(const float4*)&hi[g];
            thi[r][c] = vh.x; thi[r][c+1] = vh.y; thi[r][c+2] = vh.z; thi[r][c+3] = vh.w;
            float4 vl = *(const float4*)&lo[g];
            tlo[r][c] = vl.x; tlo[r][c+1] = vl.y; tlo[r][c+2] = vl.z; tlo[r][c+3] = vl.w;
        }
        __syncthreads();
        float spk[TC];
        #pragma unroll
        for (int t = 0; t < TC; ++t) {
            double s = (double)thi[tid][t] + (double)tlo[tid][t];
            double reset = (mem > 1.0) ? 1.0 : 0.0;
            mem = 0.9 * mem + s - reset;
            spk[t] = ((mem - 1.0) > 0.0) ? 1.0f : 0.0f;
        }
        __syncthreads();
        #pragma unroll
        for (int t = 0; t < TC; ++t) thi[tid][t] = spk[t];
        __syncthreads();
        #pragma unroll
        for (int p = 0; p < 4; ++p) {
            int id = tid + p * 256;
            int r = id / 4, c = (id % 4) * 4;
            float4 v = make_float4(thi[r][c], thi[r][c+1], thi[r][c+2], thi[r][c+3]);
            *(float4*)&hi[(row0 + r) * T_DIM + t0 + c] = v;
        }
        __syncthreads();
    }
}

extern "C" void kernel_launch(void* const* d_in, const int* in_sizes, int n_in,
                              void* d_out, int out_size, void* d_ws, size_t ws_size,
                              hipStream_t stream)
{
    const float* x = (const float*)d_in[0];
    const float* W = (const float*)d_in[1];
    float* hi = (float*)d_out;
    char* ws = (char*)d_ws;
    float* lo = (float*)(ws + LO_OFF);

    if (ws_size >= WS_NEED) {
        signed char* wsl = (signed char*)(ws + WSL_OFF);
        signed char* xsl = (signed char*)(ws + XSL_OFF);
        int* alpha = (int*)(ws + AL_OFF);
        int* beta  = (int*)(ws + BE_OFF);
        float* part = (float*)(ws + PART_OFF);

        k_aux_wx<<<dim3(2048), dim3(256), 0, stream>>>(W, wsl, alpha, x, part);
        k_slice_x<<<dim3(4, 16, B_DIM), dim3(256), 0, stream>>>(x, part, beta, xsl);
        k_oz_gemm_fused<<<dim3(1024), dim3(256), 0, stream>>>(wsl, xsl, alpha, beta, hi);
    } else {
        spk_gemm_mfma64p_kernel<<<dim3(2, 8, B_DIM), dim3(256), 0, stream>>>(x, W, hi, lo);
        spk_scan_f64_kernel<<<dim3((B_DIM * OUT_DIM) / 256), dim3(256), 0, stream>>>(hi, lo);
    }
}

// Round 11
// 310.903 us; speedup vs baseline: 1.0295x; 1.0295x over previous
//
#include <hip/hip_runtime.h>

// B=64, IN=1024, OUT=1024, T=256
// syn[b,o,t] = sum_i W[o,i]*x[b,i,t]; spikes via f64 LIF scan.
//
// R21 = best-of-both recombine after R20's regression.
// R20 post-mortem: 4-wave/1-per-SIMD hit the VGPR cap (256) and lost all
// TLP — every lgkmcnt/DMA stall fully exposed; fused 180.5->202us. The
// serial-LDS law (1129 cyc/step) was calibrated AT 2 waves/SIMD and is not
// reducible by fatter waves. REVERT fused to R19's proven 8-wave geometry.
// KEEP R20's aux restructure (k_beta deleted; slice_x computes beta inline
// from part; dual-role k_aux_wx) — verified: aux 126->118us.
// Fused kernel (R19-proven): 4-digit Ozaki p+q<=3, 20 MFMAs/wave-step,
// wave tile 32(o)x64(t), 8 waves, triple buffer 3x40KB, counted vmcnt(5),
// setprio, XCD b-swizzle, de-aliased select-form reg scan.
// Fallback: R6 f64-MFMA + standalone scan.

#define B_DIM 64
#define IN_DIM 1024
#define OUT_DIM 1024
#define T_DIM 256

typedef int v4i __attribute__((ext_vector_type(4)));
typedef int v16i __attribute__((ext_vector_type(16)));
typedef double v4d __attribute__((ext_vector_type(4)));

// ---------------- workspace layout (bytes) ----------------
#define LO_OFF   0ull                    // 67108864  f32 syn_lo (fallback only)
#define WSL_OFF  67108864ull             // i8 W frags [p:4][o32:32][ks:32][lane:64][16] = 4MB
#define XSL_OFF  73400320ull             // i8 x frags [q:4][b:64][t32:8][ks:32][lane:64][16] = 67MB
#define AL_OFF   174063616ull            // 4096      i32 alpha_e[1024]
#define BE_OFF   174067712ull            // 65536     i32 beta_e[64][256]
#define PART_OFF 174133248ull            // 1048576   f32 partial maxes [64][16][256]
#define WS_NEED  175181824ull

__device__ __forceinline__ void gload_lds16(const void* g, void* l)
{
    __builtin_amdgcn_global_load_lds(
        (const __attribute__((address_space(1))) void*)g,
        (__attribute__((address_space(3))) void*)l, 16, 0, 0);
}

// Integer digit extraction: fix28 = |x|/2^e_col * 2^28 (truncated), digits =
// 7-bit slices, negated if x<0. Bit-identical to the proven f64 trunc loop.
__device__ __forceinline__ void dig4_extract(unsigned bits, int bem,
                                             signed char* d /*4*/)
{
    const int be = (bits >> 23) & 255;
    unsigned M = (bits & 0x7fffffu) | (be ? 0x800000u : 0u);
    const int sh = be - bem + 4;
    unsigned fix = 0;
    if (sh >= 0) fix = M << sh;
    else if (sh > -32) fix = M >> (-sh);
    int d0 = (fix >> 21) & 127, d1 = (fix >> 14) & 127,
        d2 = (fix >> 7) & 127,  d3 = fix & 127;
    if (bits & 0x80000000u) { d0 = -d0; d1 = -d1; d2 = -d2; d3 = -d3; }
    d[0] = (signed char)d0; d[1] = (signed char)d1;
    d[2] = (signed char)d2; d[3] = (signed char)d3;
}

// ---------------- K1: dual-role aux (slice_w | beta_part) ----------------
__global__ __launch_bounds__(256) void k_aux_wx(
    const float* __restrict__ W, signed char* __restrict__ wsl,
    int* __restrict__ alpha_e,
    const float* __restrict__ x, float* __restrict__ part)
{
    __shared__ float red[256];
    __shared__ float wrow[1024];
    __shared__ int se;
    __shared__ float4 bp[4][64];
    const int tid = threadIdx.x;

    if (blockIdx.x < 1024) {
        // ---- slice_w (proven R15) ----
        const int o = blockIdx.x;
        float4 v = *(const float4*)&W[(size_t)o * IN_DIM + tid * 4];
        *(float4*)&wrow[tid * 4] = v;
        float m = fmaxf(fmaxf(fabsf(v.x), fabsf(v.y)), fmaxf(fabsf(v.z), fabsf(v.w)));
        red[tid] = m; __syncthreads();
        for (int s = 128; s > 0; s >>= 1) {
            if (tid < s) red[tid] = fmaxf(red[tid], red[tid + s]);
            __syncthreads();
        }
        if (tid == 0) { int e = 0; if (red[0] > 0.f) frexpf(red[0], &e); se = e; alpha_e[o] = e; }
        __syncthreads();
        if (tid >= 64) return;
        const int bem = se + 126;
        const int ks = tid >> 1, khalf = tid & 1;
        const int k0 = tid * 16;
        const int lane = (o & 31) + 32 * khalf;

        signed char dig[16][4];
        #pragma unroll
        for (int j = 0; j < 16; ++j)
            dig4_extract(__float_as_uint(wrow[k0 + j]), bem, dig[j]);

        #pragma unroll
        for (int p = 0; p < 4; ++p) {
            int w[4];
            #pragma unroll
            for (int g = 0; g < 4; ++g)
                w[g] = (dig[4*g][p] & 0xff) | ((dig[4*g+1][p] & 0xff) << 8) |
                       ((dig[4*g+2][p] & 0xff) << 16) | ((dig[4*g+3][p] & 0xff) << 24);
            const size_t base =
                (((size_t)p * 32 + (o >> 5)) * 32 + ks) * 1024 + lane * 16;
            *(v4i*)&wsl[base] = (v4i){w[0], w[1], w[2], w[3]};
        }
    } else {
        // ---- beta_part, float4 ----
        const int idx = blockIdx.x - 1024;
        const int ic = idx & 15, b = idx >> 4;
        const int quarter = tid >> 6, t4 = (tid & 63) * 4;
        const float* p = x + ((size_t)b * IN_DIM + ic * 64 + quarter * 16) * T_DIM + t4;
        float4 m4 = make_float4(0.f, 0.f, 0.f, 0.f);
        #pragma unroll
        for (int r = 0; r < 16; ++r) {
            float4 v = *(const float4*)&p[(size_t)r * T_DIM];
            m4.x = fmaxf(m4.x, fabsf(v.x)); m4.y = fmaxf(m4.y, fabsf(v.y));
            m4.z = fmaxf(m4.z, fabsf(v.z)); m4.w = fmaxf(m4.w, fabsf(v.w));
        }
        bp[quarter][tid & 63] = m4;
        __syncthreads();
        if (tid < 64) {
            float4 a = bp[0][tid], b4 = bp[1][tid], c = bp[2][tid], d = bp[3][tid];
            float4 r;
            r.x = fmaxf(fmaxf(a.x, b4.x), fmaxf(c.x, d.x));
            r.y = fmaxf(fmaxf(a.y, b4.y), fmaxf(c.y, d.y));
            r.z = fmaxf(fmaxf(a.z, b4.z), fmaxf(c.z, d.z));
            r.w = fmaxf(fmaxf(a.w, b4.w), fmaxf(c.w, d.w));
            *(float4*)&part[((size_t)b * 16 + ic) * T_DIM + tid * 4] = r;
        }
    }
}

// ---------------- K2: slice x (4 digits) + inline beta from part -----------
__global__ __launch_bounds__(256) void k_slice_x(const float* __restrict__ x,
    const float* __restrict__ part, int* __restrict__ beta_e,
    signed char* __restrict__ xsl)
{
    __shared__ float ft[64][68];   // float4-aligned rows, read 2-way free
    __shared__ int se_arr[64];
    const int tb = blockIdx.x;    // 0..3
    const int ib = blockIdx.y;    // 0..15
    const int b  = blockIdx.z;
    const int tid = threadIdx.x;
    const int t0 = tb * 64, i0 = ib * 64;
    #pragma unroll
    for (int p = 0; p < 4; ++p) {
        int id4 = tid + p * 256;           // 0..1023 float4 slots
        int il = id4 >> 4, c4 = (id4 & 15) * 4;
        float4 v = *(const float4*)&x[((size_t)b * IN_DIM + i0 + il) * T_DIM + t0 + c4];
        *(float4*)&ft[il][c4] = v;
    }
    if (tid < 64) {
        const int t = t0 + tid;
        float m = 0.f;
        #pragma unroll
        for (int ic = 0; ic < 16; ++ic)
            m = fmaxf(m, part[((size_t)b * 16 + ic) * T_DIM + t]);
        int e = 0;
        if (m > 0.f) frexpf(m, &e);
        se_arr[tid] = e;
        if (ib == 0) beta_e[b * T_DIM + t] = e;
    }
    __syncthreads();

    const int t32l = tid >> 7;
    const int ksl  = (tid >> 6) & 1;
    const int lane = tid & 63;
    const int t_local = t32l * 32 + (lane & 31);
    const int k_local = ksl * 32 + (lane >> 5) * 16;
    const int bem = se_arr[t_local] + 126;

    signed char dig[16][4];
    #pragma unroll
    for (int j = 0; j < 16; ++j)
        dig4_extract(__float_as_uint(ft[k_local + j][t_local]), bem, dig[j]);

    #pragma unroll
    for (int p = 0; p < 4; ++p) {
        int w[4];
        #pragma unroll
        for (int g = 0; g < 4; ++g)
            w[g] = (dig[4*g][p] & 0xff) | ((dig[4*g+1][p] & 0xff) << 8) |
                   ((dig[4*g+2][p] & 0xff) << 16) | ((dig[4*g+3][p] & 0xff) << 24);
        const size_t base =
            ((((size_t)p * B_DIM + b) * 8 + (tb * 2 + t32l)) * 32 + (ib * 2 + ksl)) * 1024
            + lane * 16;
        *(v4i*)&xsl[base] = (v4i){w[0], w[1], w[2], w[3]};
    }
}

// ---------------- K4: fused Ozaki i8 GEMM + LIF scan (R19-proven) ----------
// Block 64(o)x256(t), 1D grid 1024, XCD swizzle b=(r&7)*8+(r>>3), ob=bid>>6.
// 8 waves: woh=wave>>2 (o sub), wtq=wave&3 (t quarter). Wave tile 32x64,
// 20 MFMAs/step. LDS buffer (40KB): 40 segments of 1KB; segment s = 8j+wave.
// s<8 -> A [p=s>>1][osub=s&1]; s>=8 -> u=s-8, B [q=u>>3][t32=u&7].
// vmcnt(5) steady, drain once at kt=30.
#define OZ_LOADS(PF)                                                        \
    {                                                                       \
        _Pragma("unroll")                                                   \
        for (int j = 0; j < 5; ++j) {                                       \
            gload_lds16(gp[j], &LB[PF][lbase + j * 8192]);                  \
            gp[j] += 1024;                                                  \
        }                                                                   \
    }

#define OZ_MATH(CUR)                                                        \
    {                                                                       \
        const signed char* base_ = LB[CUR];                                 \
        v4i af[4];                                                          \
        _Pragma("unroll")                                                   \
        for (int p = 0; p < 4; ++p)                                         \
            af[p] = *(const v4i*)(base_ + p * 2048 + aoffm);                \
        __builtin_amdgcn_s_setprio(1);                                      \
        _Pragma("unroll")                                                   \
        for (int q = 0; q < 4; ++q) {                                       \
            v4i b0 = *(const v4i*)(base_ + q * 8192 + boffm);               \
            v4i b1 = *(const v4i*)(base_ + q * 8192 + boffm + 1024);        \
            _Pragma("unroll")                                               \
            for (int p = 0; p + q < 4; ++p) {                               \
                accA[p + q] = __builtin_amdgcn_mfma_i32_32x32x32_i8(        \
                    af[p], b0, accA[p + q], 0, 0, 0);                       \
                accB[p + q] = __builtin_amdgcn_mfma_i32_32x32x32_i8(        \
                    af[p], b1, accB[p + q], 0, 0, 0);                       \
            }                                                               \
        }                                                                   \
        __builtin_amdgcn_s_setprio(0);                                      \
    }

#define VMBAR(N)                                                            \
    do {                                                                    \
        asm volatile("s_waitcnt vmcnt(" #N ")" ::: "memory");               \
        __builtin_amdgcn_s_barrier();                                       \
    } while (0)

__global__ __launch_bounds__(512, 2) void k_oz_gemm_fused(
    const signed char* __restrict__ wsl, const signed char* __restrict__ xsl,
    const int* __restrict__ alpha_e, const int* __restrict__ beta_e,
    float* __restrict__ out)
{
    __shared__ __align__(16) signed char LB[3][40960];

    const int tid = threadIdx.x;
    const int lane = tid & 63, wave = tid >> 6;    // wave 0..7
    const int bid = blockIdx.x;
    const int ob = bid >> 6;                       // 0..15 (o block of 64)
    const int rr = bid & 63;
    const int b  = ((rr & 7) << 3) + (rr >> 3);    // bijective XCD swizzle
    const int o0 = ob * 64;
    const int woh = wave >> 2;   // o sub 0..1 (32 rows each)
    const int wtq = wave & 3;    // t quarter 0..3 (64 cols each)
    const int l16 = lane * 16;

    v16i accA[4], accB[4];
    #pragma unroll
    for (int s = 0; s < 4; ++s) {
        accA[s] = (v16i){0,0,0,0,0,0,0,0,0,0,0,0,0,0,0,0};
        accB[s] = (v16i){0,0,0,0,0,0,0,0,0,0,0,0,0,0,0,0};
    }

    // Staging pointers: segment s = 8j + wave.
    const signed char* gp[5];
    #pragma unroll
    for (int j = 0; j < 5; ++j) {
        const int s = 8 * j + wave;
        if (s < 8) {
            gp[j] = wsl + ((size_t)(s >> 1) << 20)
                        + ((size_t)(2 * ob + (s & 1)) << 15) + l16;
        } else {
            const int u = s - 8;
            gp[j] = xsl + ((size_t)(u >> 3) << 24) + ((size_t)b << 18)
                        + ((size_t)(u & 7) << 15) + l16;
        }
    }
    const int lbase = wave * 1024;   // segment s LDS offset = s*1024

    // Math-side LDS offsets.
    const int aoffm = woh * 1024 + l16;            // + p*2048 (A region [0,8192))
    const int boffm = 8192 + wtq * 2048 + l16;     // + q*8192 (B region)

    // prologue: kt=0 -> LB[0], kt=1 -> LB[1]; retire kt=0 (vmcnt 10->5).
    OZ_LOADS(0)
    OZ_LOADS(1)
    VMBAR(5);

    // steady state: kt = 0..29, buffers rotate (0,1,2). Never drain to 0.
    #pragma unroll 1
    for (int it = 0; it < 10; ++it) {
        OZ_LOADS(2) OZ_MATH(0) VMBAR(5);
        OZ_LOADS(0) OZ_MATH(1) VMBAR(5);
        OZ_LOADS(1) OZ_MATH(2) VMBAR(5);
    }
    // kt=30: drain kt=31's 5 loads, last barrier.
    OZ_MATH(0) VMBAR(0);
    // kt=31: registers only.
    OZ_MATH(1)

    // Runtime D-placement probes (R6/R7 technique).
    const int lr = lane & 31;
    const int rv = (lr + 1) * 0x01010101;
    const v4i pav  = {rv, rv, rv, rv};
    const v4i onev = {0x01010101, 0x01010101, 0x01010101, 0x01010101};
    const v16i z = (v16i){0,0,0,0,0,0,0,0,0,0,0,0,0,0,0,0};
    v16i d1 = __builtin_amdgcn_mfma_i32_32x32x32_i8(pav, onev, z, 0, 0, 0);
    v16i d2 = __builtin_amdgcn_mfma_i32_32x32x32_i8(onev, pav, z, 0, 0, 0);

    const int col = (d2[0] >> 5) - 1;            // 0..31 within tile
    const int gtA = wtq * 64 + col;              // global t of accA column
    const int gtB = gtA + 32;                    // accB column
    const int ebA = beta_e[b * T_DIM + gtA];
    const int ebB = beta_e[b * T_DIM + gtB];

    // Exact f64 syn; acc dies here.
    const double C0 = 0x1p-14, C1 = 0x1p-21, C2 = 0x1p-28, C3 = 0x1p-35;
    double synA_[16], synB_[16];
    int go_[16];
    #pragma unroll
    for (int r = 0; r < 16; ++r) {
        const int row = (d1[r] >> 5) - 1;        // 0..31 within tile
        const int go = woh * 32 + row;
        go_[r] = go;
        const int ea = alpha_e[o0 + go];
        double vA = (double)accA[0][r] * C0 + (double)accA[1][r] * C1 +
                    (double)accA[2][r] * C2 + (double)accA[3][r] * C3;
        double vB = (double)accB[0][r] * C0 + (double)accB[1][r] * C1 +
                    (double)accB[2][r] * C2 + (double)accB[3][r] * C3;
        synA_[r] = ldexp(vA, ea + ebA);
        synB_[r] = ldexp(vB, ea + ebB);
    }

    // ---- fused LIF scan over 4 t-chunks of 64 ----
    double* synbuf = (double*)&LB[0][0];   // [t:64][o:65]
    float*  spkbuf = (float*)&LB[1][0];    // [o:64][68] (float4-aligned rows)
    float*  outp = out + ((size_t)b * OUT_DIM + o0) * T_DIM;
    double mem = 0.0;                      // valid in wave 0 lanes (o-rows)

    __syncthreads();
    #pragma unroll 1
    for (int c = 0; c < 4; ++c) {
        if (wtq == c) {
            #pragma unroll
            for (int r = 0; r < 16; ++r) {
                synbuf[(size_t)col * 65 + go_[r]]        = synA_[r];
                synbuf[(size_t)(col + 32) * 65 + go_[r]] = synB_[r];
            }
        }
        __syncthreads();
        if (wave == 0) {
            // batch-16 reg reads -> short select-form chain -> packed writes.
            float sp[64];
            #pragma unroll
            for (int g = 0; g < 4; ++g) {
                double sv[16];
                #pragma unroll
                for (int k = 0; k < 16; ++k)
                    sv[k] = synbuf[(size_t)(g * 16 + k) * 65 + lane];
                #pragma unroll
                for (int k = 0; k < 16; ++k) {
                    double a = 0.9 * mem + sv[k];          // same eval order
                    mem = (mem > 1.0) ? (a - 1.0) : a;     // reset uses OLD mem
                    sp[g * 16 + k] = (mem > 1.0) ? 1.0f : 0.0f;
                }
            }
            #pragma unroll
            for (int k4 = 0; k4 < 16; ++k4)
                *(float4*)&spkbuf[lane * 68 + k4 * 4] = make_float4(
                    sp[k4 * 4], sp[k4 * 4 + 1], sp[k4 * 4 + 2], sp[k4 * 4 + 3]);
        }
        __syncthreads();
        {
            const int o = tid >> 3, tg = tid & 7;
            float4 v0 = *(float4*)&spkbuf[o * 68 + tg * 8];
            float4 v1 = *(float4*)&spkbuf[o * 68 + tg * 8 + 4];
            float* dst = outp + (size_t)o * T_DIM + c * 64 + tg * 8;
            *(float4*)&dst[0] = v0;
            *(float4*)&dst[4] = v1;
        }
        __syncthreads();
    }
}

// ---------------- Fallback GEMM: R6 f64-MFMA with probes (proven) ----------
#define BM 128
#define BN 128
#define BK 16
#define LDA 130

__global__ __launch_bounds__(256, 2) void spk_gemm_mfma64p_kernel(
    const float* __restrict__ x, const float* __restrict__ W,
    float* __restrict__ syn_hi, float* __restrict__ syn_lo)
{
    const int tid  = threadIdx.x;
    const int lane = tid & 63;
    const int wave = tid >> 6;
    const int tb = blockIdx.x, ob = blockIdx.y, b = blockIdx.z;

    __shared__ __align__(16) double As[BK][LDA];
    __shared__ __align__(16) double Bs[BK][LDA];

    const v4d zz = {0.0, 0.0, 0.0, 0.0};
    v4d d1 = __builtin_amdgcn_mfma_f64_16x16x4f64((double)lane, 1.0, zz, 0, 0, 0);
    v4d d2 = __builtin_amdgcn_mfma_f64_16x16x4f64(1.0, (double)lane, zz, 0, 0, 0);
    const bool a_h1 = (((int)d1[0] & 3) == 0);
    const bool b_h1 = (((int)d2[0] & 3) == 0);
    int drow[4];
    #pragma unroll
    for (int r = 0; r < 4; ++r) {
        const int v = (int)d1[r];
        drow[r] = (a_h1 ? (v - 96) >> 2 : (v - 6) >> 4) & 15;
    }
    const int am = a_h1 ? (lane & 15) : (lane >> 2);
    const int ak = a_h1 ? (lane >> 4) : (lane & 3);
    const int bn = b_h1 ? (lane & 15) : (lane >> 2);
    const int bk = b_h1 ? (lane >> 4) : (lane & 3);
    const int dcol = lane & 15;

    const int o0 = ob * BM, t0 = tb * BN;
    const float* Wp = W + (size_t)o0 * IN_DIM;
    const float* xp = x + (size_t)b * IN_DIM * T_DIM + t0;
    const int wo = (wave >> 1) * 64, wt = (wave & 1) * 64;

    v4d acc[4][4];
    #pragma unroll
    for (int i = 0; i < 4; ++i)
        #pragma unroll
        for (int j = 0; j < 4; ++j) acc[i][j] = zz;

    const int ar0 = tid / 4, ac = (tid % 4) * 4;
    const int bkr0 = tid / 32, btc = (tid % 32) * 4;

    float4 pa[2], pb[2];
    #pragma unroll
    for (int p = 0; p < 2; ++p) {
        pa[p] = *(const float4*)&Wp[(size_t)(ar0 + p * 64) * IN_DIM + ac];
        pb[p] = *(const float4*)&xp[(size_t)(bkr0 + p * 8) * T_DIM + btc];
    }

    for (int k0 = 0; k0 < IN_DIM; k0 += BK) {
        #pragma unroll
        for (int p = 0; p < 2; ++p) {
            const int r = ar0 + p * 64;
            As[ac + 0][r] = (double)pa[p].x; As[ac + 1][r] = (double)pa[p].y;
            As[ac + 2][r] = (double)pa[p].z; As[ac + 3][r] = (double)pa[p].w;
            const int kr = bkr0 + p * 8;
            Bs[kr][btc + 0] = (double)pb[p].x; Bs[kr][btc + 1] = (double)pb[p].y;
            Bs[kr][btc + 2] = (double)pb[p].z; Bs[kr][btc + 3] = (double)pb[p].w;
        }
        if (k0 + BK < IN_DIM) {
            #pragma unroll
            for (int p = 0; p < 2; ++p) {
                pa[p] = *(const float4*)&Wp[(size_t)(ar0 + p * 64) * IN_DIM + k0 + BK + ac];
                pb[p] = *(const float4*)&xp[(size_t)(bkr0 + p * 8 + k0 + BK) * T_DIM + btc];
            }
        }
        __syncthreads();
        #pragma unroll
        for (int kk = 0; kk < 4; ++kk) {
            const int kra = kk * 4 + ak, krb = kk * 4 + bk;
            double a[4], bb[4];
            #pragma unroll
            for (int i = 0; i < 4; ++i) a[i] = As[kra][wo + i * 16 + am];
            #pragma unroll
            for (int j = 0; j < 4; ++j) bb[j] = Bs[krb][wt + j * 16 + bn];
            #pragma unroll
            for (int i = 0; i < 4; ++i)
                #pragma unroll
                for (int j = 0; j < 4; ++j)
                    acc[i][j] = __builtin_amdgcn_mfma_f64_16x16x4f64(a[i], bb[j], acc[i][j], 0, 0, 0);
        }
        __syncthreads();
    }

    float* ohi = syn_hi + ((size_t)b * OUT_DIM + o0) * T_DIM + t0;
    float* olo = syn_lo + ((size_t)b * OUT_DIM + o0) * T_DIM + t0;
    #pragma unroll
    for (int i = 0; i < 4; ++i)
        #pragma unroll
        for (int j = 0; j < 4; ++j) {
            const int col = wt + j * 16 + dcol;
            #pragma unroll
            for (int r = 0; r < 4; ++r) {
                double s = acc[i][j][r];
                float hi = (float)s;
                float lo = (float)(s - (double)hi);
                const size_t off = (size_t)(wo + i * 16 + drow[r]) * T_DIM + col;
                ohi[off] = hi; olo[off] = lo;
            }
        }
}

// ---------------- scan: f64 LIF, in place over hi (fallback only) ----------
__global__ __launch_bounds__(256) void spk_scan_f64_kernel(
    float* __restrict__ hi, const float* __restrict__ lo)
{
    const int TC = 16;
    __shared__ float thi[256][TC + 1];
    __shared__ float tlo[256][TC + 1];
    const int tid = threadIdx.x;
    const size_t row0 = (size_t)blockIdx.x * 256;

    double mem = 0.0;
    for (int t0 = 0; t0 < T_DIM; t0 += TC) {
        #pragma unroll
        for (int p = 0; p < 4; ++p) {
            int id = tid + p * 256;
            int r = id / 4, c = (id % 4) * 4;
            size_t g = (row0 + r) * T_DIM + t0 + c;
            float4 vh = *(const float4*)&hi[g];
            thi[r][c] = vh.x; thi[r][c+1] = vh.y; thi[r][c+2] = vh.z; thi[r][c+3] = vh.w;
            float4 vl = *(const float4*)&lo[g];
            tlo[r][c] = vl.x; tlo[r][c+1] = vl.y; tlo[r][c+2] = vl.z; tlo[r][c+3] = vl.w;
        }
        __syncthreads();
        float spk[TC];
        #pragma unroll
        for (int t = 0; t < TC; ++t) {
            double s = (double)thi[tid][t] + (double)tlo[tid][t];
            double reset = (mem > 1.0) ? 1.0 : 0.0;
            mem = 0.9 * mem + s - reset;
            spk[t] = ((mem - 1.0) > 0.0) ? 1.0f : 0.0f;
        }
        __syncthreads();
        #pragma unroll
        for (int t = 0; t < TC; ++t) thi[tid][t] = spk[t];
        __syncthreads();
        #pragma unroll
        for (int p = 0; p < 4; ++p) {
            int id = tid + p * 256;
            int r = id / 4, c = (id % 4) * 4;
            float4 v = make_float4(thi[r][c], thi[r][c+1], thi[r][c+2], thi[r][c+3]);
            *(float4*)&hi[(row0 + r) * T_DIM + t0 + c] = v;
        }
        __syncthreads();
    }
}

extern "C" void kernel_launch(void* const* d_in, const int* in_sizes, int n_in,
                              void* d_out, int out_size, void* d_ws, size_t ws_size,
                              hipStream_t stream)
{
    const float* x = (const float*)d_in[0];
    const float* W = (const float*)d_in[1];
    float* hi = (float*)d_out;
    char* ws = (char*)d_ws;
    float* lo = (float*)(ws + LO_OFF);

    if (ws_size >= WS_NEED) {
        signed char* wsl = (signed char*)(ws + WSL_OFF);
        signed char* xsl = (signed char*)(ws + XSL_OFF);
        int* alpha = (int*)(ws + AL_OFF);
        int* beta  = (int*)(ws + BE_OFF);
        float* part = (float*)(ws + PART_OFF);

        k_aux_wx<<<dim3(2048), dim3(256), 0, stream>>>(W, wsl, alpha, x, part);
        k_slice_x<<<dim3(4, 16, B_DIM), dim3(256), 0, stream>>>(x, part, beta, xsl);
        k_oz_gemm_fused<<<dim3(1024), dim3(512), 0, stream>>>(wsl, xsl, alpha, beta, hi);
    } else {
        spk_gemm_mfma64p_kernel<<<dim3(2, 8, B_DIM), dim3(256), 0, stream>>>(x, W, hi, lo);
        spk_scan_f64_kernel<<<dim3((B_DIM * OUT_DIM) / 256), dim3(256), 0, stream>>>(hi, lo);
    }
}